// Round 21
// baseline (58.840 us; speedup 1.0000x reference)
//
#include <hip/hip_runtime.h>
#include <hip/hip_bf16.h>

// GQA paged-prefill attention, MI355X gfx950.
// Causal mask j<=i over concat(past,new) => only first Q_LEN (=1024) gathered
// past tokens are live. Flash-attention over tokens 0..1023 of paged cache.
//
// R21: dual-row-group waves. Each wave owns TWO independent 16-row groups
// (rows w*16.. of q-tile 2g and of q-tile 2g+1): K/V LDS reads shared
// (2x arithmetic intensity), two independent QK/softmax chains (2x ILP),
// block iteration count halves (the invariant ~5.8k-cyc latency quantum).
// All (g,h) kv-split into two EQUAL halves (g+1 tiles each) -> grid 512,
// 80KB LDS -> 2 blocks/CU. Combine merges all rows. R13 sync structure.

#define Q_STRIDE 4096
// SCALE * log2(e): softmax computed in exp2 domain (v_exp_f32 is exp2).
#define SCALE2 0.1275179114285314f
#define RESCALE_THR 8.0f
#define KSW_TILE 16384                     // bytes per (hkv, jb) tile
#define VSW_OFF  (2 * 1024 * 1024)         // Vt tiles at +2MB
#define ACC1_OFF (4 * 1024 * 1024)         // half1 acc bf16: 32768 rows x 256B
#define ML0_OFF  (ACC1_OFF + 32768 * 256)  // half0 (m,l): 32768 x 8B
#define ML1_OFF  (ML0_OFF + 32768 * 8)     // half1 (m,l): 32768 x 8B

typedef short short8 __attribute__((ext_vector_type(8)));
typedef float f32x4 __attribute__((ext_vector_type(4)));
typedef unsigned short ushort_t;
typedef unsigned int uint_t;

__device__ __forceinline__ ushort_t f2bf(float f) {
    return __builtin_bit_cast(ushort_t, __float2bfloat16(f));
}
__device__ __forceinline__ uint_t pk2(float a, float b) {
    return (uint_t)f2bf(a) | ((uint_t)f2bf(b) << 16);
}
__device__ __forceinline__ float bf2f(ushort_t u) {
    uint_t x = ((uint_t)u) << 16;
    return __builtin_bit_cast(float, x);
}

// ---------------- prep: paged fp32 -> dense swizzled bf16 (256 blocks) -----
__launch_bounds__(256)
__global__ void prep_kv(const float* __restrict__ kvc,
                        const int* __restrict__ bt,
                        char* __restrict__ wsb)
{
    __shared__ float sVt[64 * 128];
    const int bid = blockIdx.x;
    const int tid = threadIdx.x;
    if (bid < 128) {
        // K: [t 64][d 128] bf16, chunk c at byte t*256 + ((c*16)^((t&7)<<4))
        const int hkv = bid >> 4, jb = bid & 15;
        char* kout = wsb + (size_t)(hkv * 16 + jb) * KSW_TILE;
#pragma unroll
        for (int i = 0; i < 4; ++i) {
            const int u = tid + i * 256;   // t(64) x c(16)
            const int t = u >> 4, c = u & 15;
            const int gtok = jb * 64 + t;
            const int page = bt[gtok >> 4];
            const float* src = kvc + (size_t)page * 32768 + (size_t)hkv * 2048
                             + (gtok & 15) * 128 + c * 8;
            float4 a = *(const float4*)src;
            float4 b = *(const float4*)(src + 4);
            uint4 p;
            p.x = pk2(a.x, a.y); p.y = pk2(a.z, a.w);
            p.z = pk2(b.x, b.y); p.w = pk2(b.z, b.w);
            *(uint4*)(kout + t * 256 + ((c * 16) ^ ((t & 7) << 4))) = p;
        }
    } else {
        const int hkv = (bid - 128) >> 4, jb = (bid - 128) & 15;
        char* vout = wsb + VSW_OFF + (size_t)(hkv * 16 + jb) * KSW_TILE;
#pragma unroll
        for (int i = 0; i < 8; ++i) {
            const int u = tid + i * 256;   // t(64) x c4(32)
            const int t = u >> 5, c4 = u & 31;
            const int gtok = jb * 64 + t;
            const int page = bt[gtok >> 4];
            const float* src = kvc + (size_t)page * 32768 + 16384
                             + (size_t)hkv * 2048 + (gtok & 15) * 128 + c4 * 4;
            *(float4*)(sVt + t * 128 + c4 * 4) = *(const float4*)src;
        }
        __syncthreads();
        // Vt: [d 128][t 64] bf16, chunk ch at byte (d*128+16*ch)^((d&7)<<4)
#pragma unroll
        for (int i = 0; i < 4; ++i) {
            const int u = tid + i * 256;   // d(128) x ch(8)
            const int d = u >> 3, ch = u & 7;
            float v[8];
#pragma unroll
            for (int k = 0; k < 8; ++k) v[k] = sVt[(8 * ch + k) * 128 + d];
            uint4 p;
            p.x = pk2(v[0], v[1]); p.y = pk2(v[2], v[3]);
            p.z = pk2(v[4], v[5]); p.w = pk2(v[6], v[7]);
            *(uint4*)(vout + ((d * 128 + 16 * ch) ^ ((d & 7) << 4))) = p;
        }
    }
}

// ---------------- main attention ----------------
#define GLL16(G, L) __builtin_amdgcn_global_load_lds(                         \
    (const uint_t __attribute__((address_space(1)))*)(G),                     \
    (uint_t __attribute__((address_space(3)))*)(L), 16, 0, 0)

#define STAGE(JB, KB, VB) {                                                   \
    const char* ks = kvbf + (size_t)(hkv * 16 + (JB)) * KSW_TILE              \
                   + w * 4096 + lane * 16;                                    \
    const char* vs = ks + VSW_OFF;                                            \
    _Pragma("unroll")                                                         \
    for (int i = 0; i < 4; ++i) {                                             \
        GLL16(ks + i * 1024, (KB) + w * 4096 + i * 1024);                     \
        GLL16(vs + i * 1024, (VB) + w * 4096 + i * 1024);                     \
    }                                                                         \
}

// softmax + P-store for one row-group (masks already applied to SACC)
#define SOFTMAX_P(SACC, MRUN, LPART, ACC, PB) {                               \
    _Pragma("unroll")                                                         \
    for (int j = 0; j < 4; ++j) {                                             \
        float lmax = fmaxf(fmaxf(SACC[0][j], SACC[1][j]),                     \
                           fmaxf(SACC[2][j], SACC[3][j]));                    \
        if (__any(lmax > MRUN[j] + RESCALE_THR)) {                            \
            float mt = lmax;                                                  \
            _Pragma("unroll")                                                 \
            for (int off = 1; off < 16; off <<= 1)                            \
                mt = fmaxf(mt, __shfl_xor(mt, off));                          \
            const float mn = fmaxf(MRUN[j], mt);                              \
            const float alpha = exp2f(MRUN[j] - mn);                          \
            MRUN[j] = mn;                                                     \
            LPART[j] *= alpha;                                                \
            _Pragma("unroll")                                                 \
            for (int n2 = 0; n2 < 8; ++n2) ACC[n2][j] *= alpha;               \
        }                                                                     \
        float ls = 0.f;                                                       \
        _Pragma("unroll")                                                     \
        for (int n = 0; n < 4; ++n) {                                         \
            float p = exp2f(SACC[n][j] - MRUN[j]);                            \
            SACC[n][j] = p;                                                   \
            ls += p;                                                          \
        }                                                                     \
        LPART[j] += ls;                                                       \
    }                                                                         \
    _Pragma("unroll")                                                         \
    for (int n = 0; n < 4; ++n)                                               \
        _Pragma("unroll")                                                     \
        for (int j = 0; j < 4; ++j) {                                         \
            const int r = lhi * 4 + j;                                        \
            const uint_t byte = (uint_t)(r * 128)                             \
                + (((uint_t)((n * 16 + l15) * 2)) ^ ((uint_t)((r & 7) << 4)));\
            *(ushort_t*)((PB) + byte) = f2bf(SACC[n][j]);                     \
        }                                                                     \
}

__launch_bounds__(256)
__global__ void attn_main(const float* __restrict__ q,
                          const char* __restrict__ kvbf,
                          float* __restrict__ out,
                          char* __restrict__ wsb)
{
    __shared__ __align__(16) char sK[2][16384];
    __shared__ __align__(16) char sV[2][16384];
    __shared__ __align__(16) char sP[4][2][2048];   // 80KB total

    const int bid  = blockIdx.x;       // 512 = idx(256) x half(2)
    const int half = bid & 1;
    const int idx  = bid >> 1;
    const int g    = 7 - (idx >> 5);   // q-tile pair, long first
    const int h    = idx & 31;
    const int hkv  = h >> 2;
    const int nt0  = g + 1;            // equal halves: g+1 tiles each
    const int jb0  = half ? nt0 : 0;
    const int jb1  = half ? (2 * g + 2) : nt0;
    const int qbase = g * 128;
    const int tid  = threadIdx.x;
    const int w    = tid >> 6;
    const int lane = tid & 63;
    const int l15  = lane & 15;
    const int lhi  = lane >> 4;

    // ---- Q fragments for BOTH row-groups (SCALE2 folded)
    short8 qfA[4], qfB[4];
    {
        const float* qpA = q + (size_t)(qbase + w * 16 + l15) * Q_STRIDE + h * 128;
        const float* qpB = qpA + (size_t)64 * Q_STRIDE;
#pragma unroll
        for (int s = 0; s < 4; ++s) {
            const int d0 = s * 32 + lhi * 8;
            float4 a = *(const float4*)(qpA + d0);
            float4 b = *(const float4*)(qpA + d0 + 4);
            short8 v;
            v[0] = (short)f2bf(a.x * SCALE2); v[1] = (short)f2bf(a.y * SCALE2);
            v[2] = (short)f2bf(a.z * SCALE2); v[3] = (short)f2bf(a.w * SCALE2);
            v[4] = (short)f2bf(b.x * SCALE2); v[5] = (short)f2bf(b.y * SCALE2);
            v[6] = (short)f2bf(b.z * SCALE2); v[7] = (short)f2bf(b.w * SCALE2);
            qfA[s] = v;
            float4 a2 = *(const float4*)(qpB + d0);
            float4 b2 = *(const float4*)(qpB + d0 + 4);
            short8 v2;
            v2[0] = (short)f2bf(a2.x * SCALE2); v2[1] = (short)f2bf(a2.y * SCALE2);
            v2[2] = (short)f2bf(a2.z * SCALE2); v2[3] = (short)f2bf(a2.w * SCALE2);
            v2[4] = (short)f2bf(b2.x * SCALE2); v2[5] = (short)f2bf(b2.y * SCALE2);
            v2[6] = (short)f2bf(b2.z * SCALE2); v2[7] = (short)f2bf(b2.w * SCALE2);
            qfB[s] = v2;
        }
    }

    f32x4 accA[8], accB[8];
#pragma unroll
    for (int n2 = 0; n2 < 8; ++n2) {
        accA[n2] = (f32x4){0.f, 0.f, 0.f, 0.f};
        accB[n2] = (f32x4){0.f, 0.f, 0.f, 0.f};
    }
    float mA[4] = {-1e30f, -1e30f, -1e30f, -1e30f};
    float lA[4] = {0.f, 0.f, 0.f, 0.f};
    float mB[4] = {-1e30f, -1e30f, -1e30f, -1e30f};
    float lB[4] = {0.f, 0.f, 0.f, 0.f};

    STAGE(jb0, sK[0], sV[0])
    __syncthreads();

    char* pbA = sP[w][0];
    char* pbB = sP[w][1];
    for (int jb = jb0; jb < jb1; ++jb) {
        const int cur = (jb - jb0) & 1;
        char* kbuf = sK[cur];
        char* vbuf = sV[cur];
        const bool pf = (jb + 1 < jb1);
        if (pf) {
            STAGE(jb + 1, sK[cur ^ 1], sV[cur ^ 1])
            asm volatile("s_waitcnt vmcnt(8)" ::: "memory");
        } else {
            asm volatile("s_waitcnt vmcnt(0)" ::: "memory");
        }
        __builtin_amdgcn_sched_barrier(0);
        __builtin_amdgcn_s_barrier();
        __builtin_amdgcn_sched_barrier(0);

        // ---- S = Q K^T for BOTH groups: each kb read feeds 2 MFMAs
        f32x4 saccA[4], saccB[4];
#pragma unroll
        for (int n = 0; n < 4; ++n) {
            saccA[n] = (f32x4){0.f, 0.f, 0.f, 0.f};
            saccB[n] = (f32x4){0.f, 0.f, 0.f, 0.f};
        }
        __builtin_amdgcn_s_setprio(1);
#pragma unroll
        for (int s = 0; s < 4; ++s) {
#pragma unroll
            for (int n = 0; n < 4; ++n) {
                const int tok = n * 16 + l15;
                const uint_t byte = (uint_t)(tok * 256)
                    + (((uint_t)((s * 32 + lhi * 8) * 2)) ^ ((uint_t)((tok & 7) << 4)));
                short8 kb = *(const short8*)(kbuf + byte);
                saccA[n] = __builtin_amdgcn_mfma_f32_16x16x32_bf16(qfA[s], kb, saccA[n], 0, 0, 0);
                saccB[n] = __builtin_amdgcn_mfma_f32_16x16x32_bf16(qfB[s], kb, saccB[n], 0, 0, 0);
            }
        }
        __builtin_amdgcn_s_setprio(0);

        // ---- masks. A (rows qbase..+63): diag at jb==2g; jb==2g+1 masks
        // everything automatically (tok > all A rows). B: diag at jb==2g+1.
        if (jb >= 2 * g) {
#pragma unroll
            for (int n = 0; n < 4; ++n)
#pragma unroll
                for (int j = 0; j < 4; ++j) {
                    const int tok = jb * 64 + n * 16 + l15;
                    const int qg  = qbase + w * 16 + lhi * 4 + j;
                    if (tok > qg) saccA[n][j] = -1e30f;
                }
        }
        if (jb == 2 * g + 1) {
#pragma unroll
            for (int n = 0; n < 4; ++n)
#pragma unroll
                for (int j = 0; j < 4; ++j) {
                    const int tok = jb * 64 + n * 16 + l15;
                    const int qg  = qbase + 64 + w * 16 + lhi * 4 + j;
                    if (tok > qg) saccB[n][j] = -1e30f;
                }
        }

        // ---- two independent softmax chains (compiler interleaves)
        SOFTMAX_P(saccA, mA, lA, accA, pbA)
        SOFTMAX_P(saccB, mB, lB, accB, pbB)

        // ---- O += P V : each vbf read feeds 2 MFMAs
        __builtin_amdgcn_s_setprio(1);
#pragma unroll
        for (int s2 = 0; s2 < 2; ++s2) {
            const uint_t pbyte = (uint_t)(l15 * 128)
                + (((uint_t)((s2 * 32 + lhi * 8) * 2)) ^ ((uint_t)((l15 & 7) << 4)));
            short8 paA = *(const short8*)(pbA + pbyte);
            short8 paB = *(const short8*)(pbB + pbyte);
#pragma unroll
            for (int n2 = 0; n2 < 8; ++n2) {
                const int dim = n2 * 16 + l15;
                const uint_t vbyte = (uint_t)(dim * 128)
                    + (((uint_t)((s2 * 32 + lhi * 8) * 2)) ^ ((uint_t)((dim & 7) << 4)));
                short8 vbf = *(const short8*)(vbuf + vbyte);
                accA[n2] = __builtin_amdgcn_mfma_f32_16x16x32_bf16(paA, vbf, accA[n2], 0, 0, 0);
                accB[n2] = __builtin_amdgcn_mfma_f32_16x16x32_bf16(paB, vbf, accB[n2], 0, 0, 0);
            }
        }
        __builtin_amdgcn_s_setprio(0);

        if (pf) {
            __builtin_amdgcn_sched_barrier(0);
            __builtin_amdgcn_s_barrier();
            __builtin_amdgcn_sched_barrier(0);
        }
    }

    // ---- epilogue: partials for BOTH groups
#pragma unroll
    for (int j = 0; j < 4; ++j) {
        float lsA = lA[j], lsB = lB[j];
#pragma unroll
        for (int off = 1; off < 16; off <<= 1) {
            lsA += __shfl_xor(lsA, off);
            lsB += __shfl_xor(lsB, off);
        }
        const int rowA = w * 16 + lhi * 4 + j;      // row within 128-row pair
        const int rowB = rowA + 64;
        const int idxA = (g * 32 + h) * 128 + rowA;
        const int idxB = idxA + 64;
        if (half == 0) {
            float* dA = out + (size_t)(qbase + rowA) * Q_STRIDE + h * 128;
            float* dB = out + (size_t)(qbase + rowB) * Q_STRIDE + h * 128;
#pragma unroll
            for (int n2 = 0; n2 < 8; ++n2) {
                dA[n2 * 16 + l15] = accA[n2][j];    // unnormalized
                dB[n2 * 16 + l15] = accB[n2][j];
            }
            if (l15 == 0) {
                float* ml = (float*)(wsb + ML0_OFF);
                ml[(size_t)idxA * 2] = mA[j]; ml[(size_t)idxA * 2 + 1] = lsA;
                ml[(size_t)idxB * 2] = mB[j]; ml[(size_t)idxB * 2 + 1] = lsB;
            }
        } else {
            ushort_t* ab = (ushort_t*)(wsb + ACC1_OFF);
#pragma unroll
            for (int n2 = 0; n2 < 8; ++n2) {
                ab[(size_t)idxA * 128 + n2 * 16 + l15] = f2bf(accA[n2][j]);
                ab[(size_t)idxB * 128 + n2 * 16 + l15] = f2bf(accB[n2][j]);
            }
            if (l15 == 0) {
                float* ml = (float*)(wsb + ML1_OFF);
                ml[(size_t)idxA * 2] = mA[j]; ml[(size_t)idxA * 2 + 1] = lsA;
                ml[(size_t)idxB * 2] = mB[j]; ml[(size_t)idxB * 2 + 1] = lsB;
            }
        }
    }
}

// ---------------- combine (all rows; m in exp2 domain) ----------------
__launch_bounds__(256)
__global__ void attn_combine(float* __restrict__ out, const char* __restrict__ wsb)
{
    const int pid = blockIdx.x;           // 512 = g(8) x h(32) x rowhalf(2)
    const int g   = pid >> 6;
    const int h   = (pid >> 1) & 31;
    const int rh  = pid & 1;
    const int tid = threadIdx.x;
    const int d4  = (tid & 31) * 4;
    const float* ml0b = (const float*)(wsb + ML0_OFF);
    const float* ml1b = (const float*)(wsb + ML1_OFF);
    const ushort_t* a1b = (const ushort_t*)(wsb + ACC1_OFF);

#pragma unroll
    for (int p = 0; p < 8; ++p) {
        const int r = (tid >> 5) + p * 8;            // 0..63
        const int row128 = rh * 64 + r;
        const size_t idx = (size_t)(g * 32 + h) * 128 + row128;
        const float m1 = ml0b[idx * 2], l1 = ml0b[idx * 2 + 1];
        const float m2 = ml1b[idx * 2], l2 = ml1b[idx * 2 + 1];
        const float m  = fmaxf(m1, m2);
        const float a1 = exp2f(m1 - m), a2 = exp2f(m2 - m);
        const float inv = 1.0f / (l1 * a1 + l2 * a2);
        float* o = out + (size_t)(g * 128 + row128) * Q_STRIDE + h * 128 + d4;
        const ushort_t* y4 = a1b + idx * 128 + d4;
        float4 x = *(const float4*)o;
        x.x = (x.x * a1 + bf2f(y4[0]) * a2) * inv;
        x.y = (x.y * a1 + bf2f(y4[1]) * a2) * inv;
        x.z = (x.z * a1 + bf2f(y4[2]) * a2) * inv;
        x.w = (x.w * a1 + bf2f(y4[3]) * a2) * inv;
        *(float4*)o = x;
    }
}

extern "C" void kernel_launch(void* const* d_in, const int* in_sizes, int n_in,
                              void* d_out, int out_size, void* d_ws, size_t ws_size,
                              hipStream_t stream) {
    const float* q   = (const float*)d_in[0];
    // d_in[1] (k) and d_in[2] (v) are dead under the reference's causal mask.
    const float* kvc = (const float*)d_in[3];
    const int*   bt  = (const int*)d_in[4];
    float* out = (float*)d_out;
    char*  wsb = (char*)d_ws;
    prep_kv<<<dim3(256), dim3(256), 0, stream>>>(kvc, bt, wsb);
    attn_main<<<dim3(512), dim3(256), 0, stream>>>(q, wsb, out, wsb);
    attn_combine<<<dim3(512), dim3(256), 0, stream>>>(out, wsb);
}

// Round 22
// 44.572 us; speedup vs baseline: 1.3201x; 1.3201x over previous
//
#include <hip/hip_runtime.h>
#include <hip/hip_bf16.h>

// GQA paged-prefill attention, MI355X gfx950.
// Causal mask j<=i over concat(past,new) => only first Q_LEN (=1024) gathered
// past tokens are live. Flash-attention over tokens 0..1023 of paged cache.
//
// R22 = R19 (best: lagged-PV reg pipeline, exp2 softmax, counted vmcnt,
// setprio, dbuf LDS K/V) + SPLIT PREP (256 blocks: K-convert and V-transpose
// in independent blocks, halving prep critical path; validated in R21).

#define NUM_HEADS 32
#define HEAD_DIM 128
#define Q_STRIDE 4096
// SCALE * log2(e): softmax computed in exp2 domain (v_exp_f32 is exp2).
#define SCALE2 0.1275179114285314f
#define RESCALE_THR 8.0f
#define KSW_TILE 16384                 // bytes per (hkv, jb) tile
#define VSW_OFF (2 * 1024 * 1024)      // Vt tiles start 2MB into ws

typedef short short8 __attribute__((ext_vector_type(8)));
typedef float f32x4 __attribute__((ext_vector_type(4)));
typedef unsigned short ushort_t;
typedef unsigned int uint_t;

__device__ __forceinline__ ushort_t f2bf(float f) {
    return __builtin_bit_cast(ushort_t, __float2bfloat16(f));
}
__device__ __forceinline__ uint_t pk2(float a, float b) {
    return (uint_t)f2bf(a) | ((uint_t)f2bf(b) << 16);
}

// ---------------- prep: paged fp32 -> dense swizzled bf16 (256 blocks) -----
__launch_bounds__(256)
__global__ void prep_kv(const float* __restrict__ kvc,
                        const int* __restrict__ bt,
                        char* __restrict__ wsb)
{
    __shared__ float sVt[64 * 128];
    const int bid = blockIdx.x;
    const int tid = threadIdx.x;
    if (bid < 128) {
        // K: [t 64][d 128] bf16, chunk c at byte t*256 + ((c*16)^((t&7)<<4))
        const int hkv = bid >> 4, jb = bid & 15;
        char* kout = wsb + (size_t)(hkv * 16 + jb) * KSW_TILE;
#pragma unroll
        for (int i = 0; i < 4; ++i) {
            const int u = tid + i * 256;   // t(64) x c(16)
            const int t = u >> 4, c = u & 15;
            const int gtok = jb * 64 + t;
            const int page = bt[gtok >> 4];
            const float* src = kvc + (size_t)page * 32768 + (size_t)hkv * 2048
                             + (gtok & 15) * 128 + c * 8;
            float4 a = *(const float4*)src;
            float4 b = *(const float4*)(src + 4);
            uint4 p;
            p.x = pk2(a.x, a.y); p.y = pk2(a.z, a.w);
            p.z = pk2(b.x, b.y); p.w = pk2(b.z, b.w);
            *(uint4*)(kout + t * 256 + ((c * 16) ^ ((t & 7) << 4))) = p;
        }
    } else {
        const int hkv = (bid - 128) >> 4, jb = (bid - 128) & 15;
        char* vout = wsb + VSW_OFF + (size_t)(hkv * 16 + jb) * KSW_TILE;
#pragma unroll
        for (int i = 0; i < 8; ++i) {
            const int u = tid + i * 256;   // t(64) x c4(32)
            const int t = u >> 5, c4 = u & 31;
            const int gtok = jb * 64 + t;
            const int page = bt[gtok >> 4];
            const float* src = kvc + (size_t)page * 32768 + 16384
                             + (size_t)hkv * 2048 + (gtok & 15) * 128 + c4 * 4;
            *(float4*)(sVt + t * 128 + c4 * 4) = *(const float4*)src;
        }
        __syncthreads();
        // Vt: [d 128][t 64] bf16, chunk ch at byte (d*128+16*ch)^((d&7)<<4)
#pragma unroll
        for (int i = 0; i < 4; ++i) {
            const int u = tid + i * 256;   // d(128) x ch(8)
            const int d = u >> 3, ch = u & 7;
            float v[8];
#pragma unroll
            for (int k = 0; k < 8; ++k) v[k] = sVt[(8 * ch + k) * 128 + d];
            uint4 p;
            p.x = pk2(v[0], v[1]); p.y = pk2(v[2], v[3]);
            p.z = pk2(v[4], v[5]); p.w = pk2(v[6], v[7]);
            *(uint4*)(vout + ((d * 128 + 16 * ch) ^ ((d & 7) << 4))) = p;
        }
    }
}

// ---------------- main attention ----------------
#define GLL16(G, L) __builtin_amdgcn_global_load_lds(                         \
    (const uint_t __attribute__((address_space(1)))*)(G),                     \
    (uint_t __attribute__((address_space(3)))*)(L), 16, 0, 0)

// Stage tile JB: 8 gll per wave (4KB K slice + 4KB V slice).
#define STAGE(JB, KB, VB) {                                                   \
    const char* ks = kvbf + (size_t)(hkv * 16 + (JB)) * KSW_TILE              \
                   + w * 4096 + lane * 16;                                    \
    const char* vs = ks + VSW_OFF;                                            \
    _Pragma("unroll")                                                         \
    for (int i = 0; i < 4; ++i) {                                             \
        GLL16(ks + i * 1024, (KB) + w * 4096 + i * 1024);                     \
        GLL16(vs + i * 1024, (VB) + w * 4096 + i * 1024);                     \
    }                                                                         \
}

__launch_bounds__(256)
__global__ void attn_main(const float* __restrict__ q,
                          const char* __restrict__ kvbf,
                          float* __restrict__ out)
{
    __shared__ __align__(16) char sK[2][16384];
    __shared__ __align__(16) char sV[2][16384];
    __shared__ __align__(16) char sP[4][2048];

    const int bid = blockIdx.x;
    const int h   = bid & 31;
    const int qt  = 15 - (bid >> 5);   // long blocks first
    const int hkv = h >> 2;
    const int tid  = threadIdx.x;
    const int w    = tid >> 6;
    const int lane = tid & 63;
    const int l15  = lane & 15;
    const int lhi  = lane >> 4;

    // ---- Q fragments (SCALE2 folded -> exp2 domain)
    short8 qf[4];
    {
        const int qrow = qt * 64 + w * 16 + l15;
        const float* qp = q + (size_t)qrow * Q_STRIDE + h * HEAD_DIM;
#pragma unroll
        for (int s = 0; s < 4; ++s) {
            const int d0 = s * 32 + lhi * 8;
            float4 a = *(const float4*)(qp + d0);
            float4 b = *(const float4*)(qp + d0 + 4);
            short8 v;
            v[0] = (short)f2bf(a.x * SCALE2); v[1] = (short)f2bf(a.y * SCALE2);
            v[2] = (short)f2bf(a.z * SCALE2); v[3] = (short)f2bf(a.w * SCALE2);
            v[4] = (short)f2bf(b.x * SCALE2); v[5] = (short)f2bf(b.y * SCALE2);
            v[6] = (short)f2bf(b.z * SCALE2); v[7] = (short)f2bf(b.w * SCALE2);
            qf[s] = v;
        }
    }

    f32x4 acc[8];
#pragma unroll
    for (int n2 = 0; n2 < 8; ++n2) acc[n2] = (f32x4){0.f, 0.f, 0.f, 0.f};
    float m_run[4]  = {-1e30f, -1e30f, -1e30f, -1e30f};
    float l_part[4] = {0.f, 0.f, 0.f, 0.f};

    // lagged-PV register state: P fragments + V fragments of tile j-1
    short8 pap0, pap1;
    short8 vbp[2][8];

    // prologue: tile 0 -> buf 0, full drain once
    STAGE(0, sK[0], sV[0])
    __syncthreads();

    char* pb = sP[w];
    for (int jb = 0; jb <= qt; ++jb) {
        const int cur = jb & 1;
        char* kbuf = sK[cur];
        char* vbuf = sV[cur];
        const bool pf = (jb < qt);
        if (pf) {
            STAGE(jb + 1, sK[cur ^ 1], sV[cur ^ 1])
            asm volatile("s_waitcnt vmcnt(8)" ::: "memory");
        } else {
            asm volatile("s_waitcnt vmcnt(0)" ::: "memory");
        }
        __builtin_amdgcn_sched_barrier(0);
        __builtin_amdgcn_s_barrier();
        __builtin_amdgcn_sched_barrier(0);

        __builtin_amdgcn_s_setprio(1);
        // ---- lagged PV_{j-1}: register-only MFMAs, fills the MFMA pipe
        // while this tile's K ds_reads are in flight; adds into acc scaled
        // for m_{j-1} BEFORE this tile's rescale (correct online-softmax).
        if (jb > 0) {
#pragma unroll
            for (int n2 = 0; n2 < 8; ++n2) {
                acc[n2] = __builtin_amdgcn_mfma_f32_16x16x32_bf16(pap0, vbp[0][n2], acc[n2], 0, 0, 0);
                acc[n2] = __builtin_amdgcn_mfma_f32_16x16x32_bf16(pap1, vbp[1][n2], acc[n2], 0, 0, 0);
            }
        }

        // ---- S = Q K^T
        f32x4 sacc[4];
#pragma unroll
        for (int n = 0; n < 4; ++n) sacc[n] = (f32x4){0.f, 0.f, 0.f, 0.f};
#pragma unroll
        for (int s = 0; s < 4; ++s) {
#pragma unroll
            for (int n = 0; n < 4; ++n) {
                const int tok = n * 16 + l15;
                const uint_t byte = (uint_t)(tok * 256)
                    + (((uint_t)((s * 32 + lhi * 8) * 2)) ^ ((uint_t)((tok & 7) << 4)));
                short8 kb = *(const short8*)(kbuf + byte);
                sacc[n] = __builtin_amdgcn_mfma_f32_16x16x32_bf16(qf[s], kb, sacc[n], 0, 0, 0);
            }
        }
        __builtin_amdgcn_s_setprio(0);

        // ---- softmax (exp2 domain) with deferred max; VALU chain overlaps
        // the lagged-PV MFMAs still draining (no data dep until rescale).
        const bool diag = (jb == qt);
        if (diag) {
#pragma unroll
            for (int n = 0; n < 4; ++n)
#pragma unroll
                for (int j = 0; j < 4; ++j) {
                    const int tok = jb * 64 + n * 16 + l15;
                    const int qg  = qt * 64 + w * 16 + lhi * 4 + j;
                    if (tok > qg) sacc[n][j] = -1e30f;
                }
        }
#pragma unroll
        for (int j = 0; j < 4; ++j) {
            float lmax = fmaxf(fmaxf(sacc[0][j], sacc[1][j]),
                               fmaxf(sacc[2][j], sacc[3][j]));
            if (__any(lmax > m_run[j] + RESCALE_THR)) {
                float mt = lmax;
#pragma unroll
                for (int off = 1; off < 16; off <<= 1)
                    mt = fmaxf(mt, __shfl_xor(mt, off));
                const float mn = fmaxf(m_run[j], mt);
                const float alpha = exp2f(m_run[j] - mn);
                m_run[j] = mn;
                l_part[j] *= alpha;
#pragma unroll
                for (int n2 = 0; n2 < 8; ++n2) acc[n2][j] *= alpha;
            }
            float ls = 0.f;
#pragma unroll
            for (int n = 0; n < 4; ++n) {
                float p = exp2f(sacc[n][j] - m_run[j]);
                sacc[n][j] = p;
                ls += p;
            }
            l_part[j] += ls;
        }

        // ---- P_j -> per-wave LDS (A-fragment relayout); same-wave lgkmcnt
#pragma unroll
        for (int n = 0; n < 4; ++n)
#pragma unroll
            for (int j = 0; j < 4; ++j) {
                const int r = lhi * 4 + j;
                const uint_t byte = (uint_t)(r * 128)
                    + (((uint_t)((n * 16 + l15) * 2)) ^ ((uint_t)((r & 7) << 4)));
                *(ushort_t*)(pb + byte) = f2bf(sacc[n][j]);
            }

        // ---- pull P_j A-fragments and V_j fragments into registers for the
        // NEXT iteration's lagged PV (no MFMA consumes them this iter).
        {
            const uint_t pbyte0 = (uint_t)(l15 * 128)
                + (((uint_t)((lhi * 8) * 2)) ^ ((uint_t)((l15 & 7) << 4)));
            pap0 = *(const short8*)(pb + pbyte0);
            const uint_t pbyte1 = (uint_t)(l15 * 128)
                + (((uint_t)((32 + lhi * 8) * 2)) ^ ((uint_t)((l15 & 7) << 4)));
            pap1 = *(const short8*)(pb + pbyte1);
        }
#pragma unroll
        for (int s2 = 0; s2 < 2; ++s2)
#pragma unroll
            for (int n2 = 0; n2 < 8; ++n2) {
                const int dim = n2 * 16 + l15;
                const uint_t vbyte = (uint_t)(dim * 128)
                    + (((uint_t)((s2 * 32 + lhi * 8) * 2)) ^ ((uint_t)((dim & 7) << 4)));
                vbp[s2][n2] = *(const short8*)(vbuf + vbyte);
            }

        if (pf) {
            // my V/P ds_reads must complete before any wave's next STAGE
            // overwrites this buffer pair
            asm volatile("s_waitcnt lgkmcnt(0)" ::: "memory");
            __builtin_amdgcn_sched_barrier(0);
            __builtin_amdgcn_s_barrier();
            __builtin_amdgcn_sched_barrier(0);
        }
    }

    // ---- final lagged PV (last tile)
    asm volatile("s_waitcnt lgkmcnt(0)" ::: "memory");
    __builtin_amdgcn_sched_barrier(0);
#pragma unroll
    for (int n2 = 0; n2 < 8; ++n2) {
        acc[n2] = __builtin_amdgcn_mfma_f32_16x16x32_bf16(pap0, vbp[0][n2], acc[n2], 0, 0, 0);
        acc[n2] = __builtin_amdgcn_mfma_f32_16x16x32_bf16(pap1, vbp[1][n2], acc[n2], 0, 0, 0);
    }

    // ---- epilogue: reduce per-lane l across 16-lane row group, store
#pragma unroll
    for (int j = 0; j < 4; ++j) {
        float lsum = l_part[j];
#pragma unroll
        for (int off = 1; off < 16; off <<= 1)
            lsum += __shfl_xor(lsum, off);
        const float inv = 1.0f / lsum;
        const int qg = qt * 64 + w * 16 + lhi * 4 + j;
        float* dst = out + (size_t)qg * Q_STRIDE + h * HEAD_DIM;
#pragma unroll
        for (int n2 = 0; n2 < 8; ++n2)
            dst[n2 * 16 + l15] = acc[n2][j] * inv;
    }
}

extern "C" void kernel_launch(void* const* d_in, const int* in_sizes, int n_in,
                              void* d_out, int out_size, void* d_ws, size_t ws_size,
                              hipStream_t stream) {
    const float* q   = (const float*)d_in[0];
    // d_in[1] (k) and d_in[2] (v) are dead under the reference's causal mask.
    const float* kvc = (const float*)d_in[3];
    const int*   bt  = (const int*)d_in[4];
    float* out = (float*)d_out;
    char*  wsb = (char*)d_ws;
    prep_kv<<<dim3(256), dim3(256), 0, stream>>>(kvc, bt, wsb);
    attn_main<<<dim3(512), dim3(256), 0, stream>>>(q, wsb, out);
}